// Round 12
// baseline (129.971 us; speedup 1.0000x reference)
//
#include <hip/hip_runtime.h>
#include <stdint.h>

#define NN 4096
#define LOG2E 1.44269504088896340736f

typedef float f32x4 __attribute__((ext_vector_type(4)));
typedef short s16x8 __attribute__((ext_vector_type(8)));
typedef unsigned u32x4 __attribute__((ext_vector_type(4)));
typedef _Float16 f16x2 __attribute__((ext_vector_type(2)));

static __device__ __forceinline__ unsigned f32_to_bf16_rne(float f) {
    unsigned u = __builtin_bit_cast(unsigned, f);
    return (u + 0x7FFFu + ((u >> 16) & 1u)) >> 16;
}
static __device__ __forceinline__ unsigned f16bits(float f) {
    _Float16 h = (_Float16)f;
    return (unsigned)__builtin_bit_cast(unsigned short, h);
}

// ---------------------------------------------------------------------------
// K01: fused adjacency-pack (blocks 0..2047) + Wx GEMM (blocks 2048..2303).
// VERBATIM from R11 (129.3 us, absmax 0.0156).
// ---------------------------------------------------------------------------
__global__ __launch_bounds__(256) void k01(const unsigned* __restrict__ adj_raw,
                                           const float* __restrict__ x,
                                           const float* __restrict__ W,
                                           const float* __restrict__ a,
                                           unsigned* __restrict__ bits,
                                           unsigned* __restrict__ wxb16,
                                           float* __restrict__ ai_s,
                                           unsigned* __restrict__ ejfj) {
    const int t = threadIdx.x;
    if (blockIdx.x < 2048) {
        __shared__ int s_i32;
        if (t == 0) {
            int all_small = 1;
            for (int i = 0; i < 32; ++i) all_small &= (adj_raw[i] <= 1u);
            s_i32 = all_small;
        }
        __syncthreads();
        const long o = (long)blockIdx.x * 256 + t;
        unsigned mm = 0;
        if (s_i32) {
            const u32x4* p = (const u32x4*)adj_raw + o * 8;  // 32 ints
            #pragma unroll
            for (int g = 0; g < 8; ++g) {
                u32x4 v = p[g];
                mm |= (v.x & 1u) << (g * 4) | (v.y & 1u) << (g * 4 + 1) |
                      (v.z & 1u) << (g * 4 + 2) | (v.w & 1u) << (g * 4 + 3);
            }
        } else {
            const u32x4* p = (const u32x4*)adj_raw + o * 2;  // 32 bytes
            #pragma unroll
            for (int g = 0; g < 2; ++g) {
                u32x4 v = p[g];
                unsigned d[4] = {v.x, v.y, v.z, v.w};
                #pragma unroll
                for (int qq = 0; qq < 4; ++qq)
                    #pragma unroll
                    for (int b = 0; b < 4; ++b)
                        mm |= ((d[qq] >> (8 * b)) & 1u) << (g * 16 + qq * 4 + b);
            }
        }
        bits[o] = mm;
        return;
    }

    // ---- Wx GEMM path ----
    __shared__ unsigned short WL[128 * 136];
    __shared__ unsigned short XL[16 * 136];
    __shared__ float WxF[16 * 132];

    const int bid = blockIdx.x - 2048;
    const int i0 = bid * 16;

    for (int p4 = t; p4 < 4096; p4 += 256) {
        f32x4 w4 = *(const f32x4*)(W + 4 * p4);
        unsigned lo = f32_to_bf16_rne(w4.x) | (f32_to_bf16_rne(w4.y) << 16);
        unsigned hi = f32_to_bf16_rne(w4.z) | (f32_to_bf16_rne(w4.w) << 16);
        int c = (4 * p4) >> 7, k = (4 * p4) & 127;
        *(unsigned long long*)&WL[c * 136 + k] =
            (unsigned long long)lo | ((unsigned long long)hi << 32);
    }
    for (int p4 = t; p4 < 512; p4 += 256) {
        f32x4 x4 = *(const f32x4*)(x + (long)i0 * 128 + 4 * p4);
        unsigned lo = f32_to_bf16_rne(x4.x) | (f32_to_bf16_rne(x4.y) << 16);
        unsigned hi = f32_to_bf16_rne(x4.z) | (f32_to_bf16_rne(x4.w) << 16);
        int r = (4 * p4) >> 7, k = (4 * p4) & 127;
        *(unsigned long long*)&XL[r * 136 + k] =
            (unsigned long long)lo | ((unsigned long long)hi << 32);
    }
    __syncthreads();

    const int w = t >> 6, l = t & 63, m = l & 15, q = l >> 4;
    f32x4 acc0 = {0.f, 0.f, 0.f, 0.f}, acc1 = {0.f, 0.f, 0.f, 0.f};
    #pragma unroll
    for (int ks = 0; ks < 4; ++ks) {
        s16x8 af = *(const s16x8*)&XL[m * 136 + ks * 32 + q * 8];
        s16x8 b0 = *(const s16x8*)&WL[(w * 32 + m) * 136 + ks * 32 + q * 8];
        s16x8 b1 = *(const s16x8*)&WL[(w * 32 + 16 + m) * 136 + ks * 32 + q * 8];
        acc0 = __builtin_amdgcn_mfma_f32_16x16x32_bf16(af, b0, acc0, 0, 0, 0);
        acc1 = __builtin_amdgcn_mfma_f32_16x16x32_bf16(af, b1, acc1, 0, 0, 0);
    }
    const int jblk = i0 >> 5;
    const int qslot = ((i0 & 16) + q * 4) >> 3;
    const int dhalf = q & 1;
    #pragma unroll
    for (int j2 = 0; j2 < 2; ++j2) {
        const int fblk = 2 * w + j2;
        f32x4 acc = j2 ? acc1 : acc0;
        unsigned d01 = f16bits(acc[0]) | (f16bits(acc[1]) << 16);
        unsigned d23 = f16bits(acc[2]) | (f16bits(acc[3]) << 16);
        unsigned* wp = wxb16 + (((jblk * 8 + fblk) * 64 + qslot * 16 + m) << 2) + dhalf * 2;
        wp[0] = d01;
        wp[1] = d23;
        #pragma unroll
        for (int reg = 0; reg < 4; ++reg)
            WxF[(q * 4 + reg) * 132 + fblk * 16 + m] = acc[reg];
    }
    __syncthreads();
    if (t < 64) {
        int r = t >> 2, h = t & 3;
        float s_i = 0.f, s_j = 0.f;
        const float* ar = a + h * 64;
        #pragma unroll
        for (int d = 0; d < 32; ++d) {
            float wv = WxF[r * 132 + h * 32 + d];
            s_i += wv * ar[d];
            s_j += wv * ar[32 + d];
        }
        ai_s[(i0 + r) * 4 + h] = s_i * LOG2E;
        float sjl = s_j * LOG2E;
        ejfj[h * NN + i0 + r] = f16bits(exp2f(sjl)) | (f16bits(exp2f(0.2f * sjl)) << 16);
    }
}

// ---------------------------------------------------------------------------
// K2: masked softmax numerator + PV partials.  Grid 512 = 256 i-tiles x 2
// j-halves; 1024 threads (16 waves = head h x parity p).  Per block stages
// only its j-half: efL 32 KB + maskL 4.4 KB + C 8 KB ~= 45 KB -> 2+ blocks/CU
// resident (32 waves/CU, 2x R11's TLP).  Inner loop VERBATIM R11 (proven).
// Partial C (f32) and l per j-half go to global; K3 finishes LN.
// ---------------------------------------------------------------------------
__global__ __launch_bounds__(1024, 4) void k2_attn(
        const unsigned* __restrict__ adjbits,
        const unsigned* __restrict__ wxb16,
        const float* __restrict__ ai_s,
        const unsigned* __restrict__ ejfj,
        float* __restrict__ Cbuf,     // [2][4096][128]
        float* __restrict__ lbuf) {   // [2][4096][4]
    __shared__ unsigned efL[4][2048];    // 32 KB: (E|F<<16), this j-half
    __shared__ unsigned maskL[16][68];   // 4.4 KB
    __shared__ float C_lds[4][16][32];   // 8 KB
    __shared__ float l_lds[4][16];

    const int t = threadIdx.x;
    const int i0 = (blockIdx.x >> 1) * 16;
    const int jh = blockIdx.x & 1;
    const int ksb = jh * 64;             // ks range [ksb, ksb+64)
    const int w = t >> 6, l = t & 63;
    const int h = w & 3, p = w >> 2;     // p in 0..3
    const int m = l & 15, q = l >> 4;

    {   // stage ejfj j-half (all 4 heads): 2048 u32x4, 2/thread, coalesced
        #pragma unroll
        for (int g = 0; g < 2; ++g) {
            int v = t + 1024 * g;        // u32x4 index
            int head = v >> 9, off = v & 511;
            ((u32x4*)&efL[head][0])[off] =
                ((const u32x4*)(ejfj + head * NN + jh * 2048))[off];
        }
    }
    {   // stage adjacency bitmask rows i0..i0+15, this j-half (64 words/row)
        int r = t >> 6, c = t & 63;
        maskL[r][c] = adjbits[(long)(i0 + r) * 128 + ksb + c];
    }
    const float aif = ai_s[(i0 + m) * 4 + h];
    const _Float16 eiH = (_Float16)exp2f(aif);
    const _Float16 fiH = (_Float16)exp2f(0.2f * aif);
    const f16x2 Ei2 = {eiH, eiH};
    const f16x2 Fi2 = {fiH, fiH};
    __syncthreads();

    const unsigned* bp16 = wxb16 + ((2 * h) * 64 + l) * 4;  // + ks*2048 dwords
    const unsigned* efh = &efL[h][0] + q * 8;               // indexed by ks-ksb
    const s16x8 ONESH = {0x3C00, 0x3C00, 0x3C00, 0x3C00,
                         0x3C00, 0x3C00, 0x3C00, 0x3C00};

    f32x4 acc0 = {0.f, 0.f, 0.f, 0.f}, acc1 = {0.f, 0.f, 0.f, 0.f};
    f32x4 accl = {0.f, 0.f, 0.f, 0.f};

    // 2-deep B prefetch  [R11 pattern, bounds adjusted to the j-half]
    const int ks0 = ksb + p;
    const int ks1 = (p + 4 < 64) ? ks0 + 4 : ks0;
    u32x4 pa0 = *(const u32x4*)(bp16 + ks0 * 2048);
    u32x4 pb0 = *(const u32x4*)(bp16 + ks0 * 2048 + 256);
    u32x4 pa1 = *(const u32x4*)(bp16 + ks1 * 2048);
    u32x4 pb1 = *(const u32x4*)(bp16 + ks1 * 2048 + 256);

    for (int ks = ks0; ks < ksb + 64; ks += 4) {   // 16 steps/wave
        const int ksn2 = (ks + 8 < ksb + 64) ? (ks + 8) : ks;
        u32x4 pa2 = *(const u32x4*)(bp16 + ksn2 * 2048);
        u32x4 pb2 = *(const u32x4*)(bp16 + ksn2 * 2048 + 256);

        const int kl = ks - ksb;
        unsigned mq = (maskL[m][kl] >> (q * 8)) & 0xffu;
        u32x4 ef0 = *(const u32x4*)(efh + kl * 32);
        u32x4 ef1 = *(const u32x4*)(efh + kl * 32 + 4);
        unsigned efu[8] = {ef0.x, ef0.y, ef0.z, ef0.w, ef1.x, ef1.y, ef1.z, ef1.w};

        union { s16x8 v; unsigned u[4]; } af;
        #pragma unroll
        for (int pr = 0; pr < 4; ++pr) {
            unsigned d0 = efu[2 * pr], d1 = efu[2 * pr + 1];
            unsigned Ep = __builtin_amdgcn_perm(d1, d0, 0x05040100);
            unsigned Fp = __builtin_amdgcn_perm(d1, d0, 0x07060302);
            f16x2 mE = Ei2 * __builtin_bit_cast(f16x2, Ep);
            f16x2 mF = Fi2 * __builtin_bit_cast(f16x2, Fp);
            f16x2 mx = __builtin_elementwise_max(mE, mF);
            unsigned lo = (unsigned)(-(int)((mq >> (2 * pr)) & 1u));
            unsigned hi = (unsigned)(-(int)((mq >> (2 * pr + 1)) & 1u));
            unsigned msk = (lo & 0xFFFFu) | (hi & 0xFFFF0000u);
            af.u[pr] = __builtin_bit_cast(unsigned, mx) & msk;
        }
        union { u32x4 u; s16x8 s; } b0c, b1c;
        b0c.u = pa0; b1c.u = pb0;
        acc0 = __builtin_amdgcn_mfma_f32_16x16x32_f16(af.v, b0c.s, acc0, 0, 0, 0);
        acc1 = __builtin_amdgcn_mfma_f32_16x16x32_f16(af.v, b1c.s, acc1, 0, 0, 0);
        accl = __builtin_amdgcn_mfma_f32_16x16x32_f16(af.v, ONESH, accl, 0, 0, 0);
        pa0 = pa1; pb0 = pb1; pa1 = pa2; pb1 = pb2;
    }

    // combine the 4 parity partials  [R11 verbatim]
    if (p == 0) {
        #pragma unroll
        for (int reg = 0; reg < 4; ++reg) {
            C_lds[h][q * 4 + reg][m] = acc0[reg];
            C_lds[h][q * 4 + reg][16 + m] = acc1[reg];
            if (m == 0) l_lds[h][q * 4 + reg] = accl[reg];
        }
    }
    __syncthreads();
    if (p == 1) {
        #pragma unroll
        for (int reg = 0; reg < 4; ++reg) {
            C_lds[h][q * 4 + reg][m] += acc0[reg];
            C_lds[h][q * 4 + reg][16 + m] += acc1[reg];
            if (m == 0) l_lds[h][q * 4 + reg] += accl[reg];
        }
    }
    __syncthreads();
    if (p == 2) {
        #pragma unroll
        for (int reg = 0; reg < 4; ++reg) {
            C_lds[h][q * 4 + reg][m] += acc0[reg];
            C_lds[h][q * 4 + reg][16 + m] += acc1[reg];
            if (m == 0) l_lds[h][q * 4 + reg] += accl[reg];
        }
    }
    __syncthreads();
    if (p == 3) {
        #pragma unroll
        for (int reg = 0; reg < 4; ++reg) {
            C_lds[h][q * 4 + reg][m] += acc0[reg];
            C_lds[h][q * 4 + reg][16 + m] += acc1[reg];
            if (m == 0) l_lds[h][q * 4 + reg] += accl[reg];
        }
    }
    __syncthreads();

    // write partials (coalesced f32x4; same index map as the old epilogue)
    if (t < 512) {
        const int r = t >> 5, c32 = t & 31;
        const int f0 = c32 * 4;
        const int hh = f0 >> 5, cl = f0 & 31;
        f32x4 cv;
        #pragma unroll
        for (int kk = 0; kk < 4; ++kk) cv[kk] = C_lds[hh][r][cl + kk];
        *(f32x4*)(Cbuf + (long)jh * NN * 128 + (long)(i0 + r) * 128 + f0) = cv;
    }
    if (t < 64) {
        int r = t >> 2, hh = t & 3;
        lbuf[(long)jh * NN * 4 + (i0 + r) * 4 + hh] = l_lds[hh][r];
    }
}

// ---------------------------------------------------------------------------
// K3: combine j-half partials, normalize, residual, LayerNorm.
// 256 blocks x 512 threads (16 rows, 32 threads/row) — epilogue code VERBATIM
// from R11 with C = C0+C1, l = l0+l1.
// ---------------------------------------------------------------------------
__global__ __launch_bounds__(512) void k3_ln(const float* __restrict__ x,
                                             const float* __restrict__ Cbuf,
                                             const float* __restrict__ lbuf,
                                             const float* __restrict__ gamma,
                                             const float* __restrict__ beta,
                                             float* __restrict__ out) {
    const int t = threadIdx.x;
    const int i0 = blockIdx.x * 16;
    const int r = t >> 5, c32 = t & 31;
    const int f0 = c32 * 4;
    const int hh = f0 >> 5;
    const long row = i0 + r;

    f32x4 c0 = *(const f32x4*)(Cbuf + row * 128 + f0);
    f32x4 c1 = *(const f32x4*)(Cbuf + (long)NN * 128 + row * 128 + f0);
    const float lsum = lbuf[row * 4 + hh] + lbuf[(long)NN * 4 + row * 4 + hh];
    const float linv = 1.0f / lsum;
    f32x4 xv = *(const f32x4*)(x + row * 128 + f0);
    float y[4], s1 = 0.f, s2 = 0.f;
    #pragma unroll
    for (int kk = 0; kk < 4; ++kk) {
        float yy = (c0[kk] + c1[kk]) * linv + xv[kk];
        y[kk] = yy; s1 += yy; s2 += yy * yy;
    }
    #pragma unroll
    for (int s = 1; s <= 16; s <<= 1) {
        s1 += __shfl_xor(s1, s, 64);
        s2 += __shfl_xor(s2, s, 64);
    }
    const float mean = s1 * (1.0f / 128.0f);
    const float var = s2 * (1.0f / 128.0f) - mean * mean;
    const float rstd = rsqrtf(var + 1e-5f);
    f32x4 gv = *(const f32x4*)(gamma + f0);
    f32x4 bv = *(const f32x4*)(beta + f0);
    f32x4 ov;
    #pragma unroll
    for (int kk = 0; kk < 4; ++kk)
        ov[kk] = gv[kk] * ((y[kk] - mean) * rstd) + bv[kk];
    *(f32x4*)(out + row * 128 + f0) = ov;
}

extern "C" void kernel_launch(void* const* d_in, const int* in_sizes, int n_in,
                              void* d_out, int out_size, void* d_ws, size_t ws_size,
                              hipStream_t stream) {
    const float* x = (const float*)d_in[0];
    const unsigned* adj_raw = (const unsigned*)d_in[1];
    const float* W = (const float*)d_in[2];
    const float* a = (const float*)d_in[3];
    const float* gamma = (const float*)d_in[4];
    const float* beta = (const float*)d_in[5];

    unsigned* wxb16 = (unsigned*)d_ws;                                  // 1 MB
    float* ai_s = (float*)((char*)d_ws + (1 << 20));                    // 64 KB
    unsigned* ejfj = (unsigned*)((char*)d_ws + (1 << 20) + (64 << 10)); // 64 KB
    unsigned* adjbits = (unsigned*)((char*)d_ws + (2 << 20));           // 2 MB
    float* Cbuf = (float*)((char*)d_ws + (4 << 20));                    // 4 MB
    float* lbuf = (float*)((char*)d_ws + (8 << 20));                    // 128 KB

    k01<<<2304, 256, 0, stream>>>(adj_raw, x, W, a, adjbits, wxb16, ai_s, ejfj);
    k2_attn<<<512, 1024, 0, stream>>>(adjbits, wxb16, ai_s, ejfj, Cbuf, lbuf);
    k3_ln<<<256, 512, 0, stream>>>(x, Cbuf, lbuf, gamma, beta, (float*)d_out);
}

// Round 13
// 129.514 us; speedup vs baseline: 1.0035x; 1.0035x over previous
//
#include <hip/hip_runtime.h>
#include <stdint.h>

#define NN 4096
#define LOG2E 1.44269504088896340736f

typedef float f32x4 __attribute__((ext_vector_type(4)));
typedef short s16x8 __attribute__((ext_vector_type(8)));
typedef unsigned u32x4 __attribute__((ext_vector_type(4)));
typedef _Float16 f16x2 __attribute__((ext_vector_type(2)));

static __device__ __forceinline__ unsigned f32_to_bf16_rne(float f) {
    unsigned u = __builtin_bit_cast(unsigned, f);
    return (u + 0x7FFFu + ((u >> 16) & 1u)) >> 16;
}
static __device__ __forceinline__ unsigned f16bits(float f) {
    _Float16 h = (_Float16)f;
    return (unsigned)__builtin_bit_cast(unsigned short, h);
}

// ---------------------------------------------------------------------------
// K01: fused adjacency-pack (blocks 0..2047) + Wx GEMM (blocks 2048..2303).
// VERBATIM from R11 (129.3 us, absmax 0.0156 — session best).
// ---------------------------------------------------------------------------
__global__ __launch_bounds__(256) void k01(const unsigned* __restrict__ adj_raw,
                                           const float* __restrict__ x,
                                           const float* __restrict__ W,
                                           const float* __restrict__ a,
                                           unsigned* __restrict__ bits,
                                           unsigned* __restrict__ wxb16,
                                           float* __restrict__ ai_s,
                                           unsigned* __restrict__ ejfj) {
    const int t = threadIdx.x;
    if (blockIdx.x < 2048) {
        __shared__ int s_i32;
        if (t == 0) {
            int all_small = 1;
            for (int i = 0; i < 32; ++i) all_small &= (adj_raw[i] <= 1u);
            s_i32 = all_small;
        }
        __syncthreads();
        const long o = (long)blockIdx.x * 256 + t;
        unsigned mm = 0;
        if (s_i32) {
            const u32x4* p = (const u32x4*)adj_raw + o * 8;  // 32 ints
            #pragma unroll
            for (int g = 0; g < 8; ++g) {
                u32x4 v = p[g];
                mm |= (v.x & 1u) << (g * 4) | (v.y & 1u) << (g * 4 + 1) |
                      (v.z & 1u) << (g * 4 + 2) | (v.w & 1u) << (g * 4 + 3);
            }
        } else {
            const u32x4* p = (const u32x4*)adj_raw + o * 2;  // 32 bytes
            #pragma unroll
            for (int g = 0; g < 2; ++g) {
                u32x4 v = p[g];
                unsigned d[4] = {v.x, v.y, v.z, v.w};
                #pragma unroll
                for (int qq = 0; qq < 4; ++qq)
                    #pragma unroll
                    for (int b = 0; b < 4; ++b)
                        mm |= ((d[qq] >> (8 * b)) & 1u) << (g * 16 + qq * 4 + b);
            }
        }
        bits[o] = mm;
        return;
    }

    // ---- Wx GEMM path ----
    __shared__ unsigned short WL[128 * 136];
    __shared__ unsigned short XL[16 * 136];
    __shared__ float WxF[16 * 132];

    const int bid = blockIdx.x - 2048;
    const int i0 = bid * 16;

    for (int p4 = t; p4 < 4096; p4 += 256) {
        f32x4 w4 = *(const f32x4*)(W + 4 * p4);
        unsigned lo = f32_to_bf16_rne(w4.x) | (f32_to_bf16_rne(w4.y) << 16);
        unsigned hi = f32_to_bf16_rne(w4.z) | (f32_to_bf16_rne(w4.w) << 16);
        int c = (4 * p4) >> 7, k = (4 * p4) & 127;
        *(unsigned long long*)&WL[c * 136 + k] =
            (unsigned long long)lo | ((unsigned long long)hi << 32);
    }
    for (int p4 = t; p4 < 512; p4 += 256) {
        f32x4 x4 = *(const f32x4*)(x + (long)i0 * 128 + 4 * p4);
        unsigned lo = f32_to_bf16_rne(x4.x) | (f32_to_bf16_rne(x4.y) << 16);
        unsigned hi = f32_to_bf16_rne(x4.z) | (f32_to_bf16_rne(x4.w) << 16);
        int r = (4 * p4) >> 7, k = (4 * p4) & 127;
        *(unsigned long long*)&XL[r * 136 + k] =
            (unsigned long long)lo | ((unsigned long long)hi << 32);
    }
    __syncthreads();

    const int w = t >> 6, l = t & 63, m = l & 15, q = l >> 4;
    f32x4 acc0 = {0.f, 0.f, 0.f, 0.f}, acc1 = {0.f, 0.f, 0.f, 0.f};
    #pragma unroll
    for (int ks = 0; ks < 4; ++ks) {
        s16x8 af = *(const s16x8*)&XL[m * 136 + ks * 32 + q * 8];
        s16x8 b0 = *(const s16x8*)&WL[(w * 32 + m) * 136 + ks * 32 + q * 8];
        s16x8 b1 = *(const s16x8*)&WL[(w * 32 + 16 + m) * 136 + ks * 32 + q * 8];
        acc0 = __builtin_amdgcn_mfma_f32_16x16x32_bf16(af, b0, acc0, 0, 0, 0);
        acc1 = __builtin_amdgcn_mfma_f32_16x16x32_bf16(af, b1, acc1, 0, 0, 0);
    }
    // f16 B-frag store (R5/R8-proven indices)
    const int jblk = i0 >> 5;
    const int qslot = ((i0 & 16) + q * 4) >> 3;
    const int dhalf = q & 1;
    #pragma unroll
    for (int j2 = 0; j2 < 2; ++j2) {
        const int fblk = 2 * w + j2;
        f32x4 acc = j2 ? acc1 : acc0;
        unsigned d01 = f16bits(acc[0]) | (f16bits(acc[1]) << 16);
        unsigned d23 = f16bits(acc[2]) | (f16bits(acc[3]) << 16);
        unsigned* wp = wxb16 + (((jblk * 8 + fblk) * 64 + qslot * 16 + m) << 2) + dhalf * 2;
        wp[0] = d01;
        wp[1] = d23;
        #pragma unroll
        for (int reg = 0; reg < 4; ++reg)
            WxF[(q * 4 + reg) * 132 + fblk * 16 + m] = acc[reg];
    }
    __syncthreads();
    if (t < 64) {
        int r = t >> 2, h = t & 3;
        float s_i = 0.f, s_j = 0.f;
        const float* ar = a + h * 64;
        #pragma unroll
        for (int d = 0; d < 32; ++d) {
            float wv = WxF[r * 132 + h * 32 + d];
            s_i += wv * ar[d];
            s_j += wv * ar[32 + d];
        }
        ai_s[(i0 + r) * 4 + h] = s_i * LOG2E;
        float sjl = s_j * LOG2E;
        ejfj[h * NN + i0 + r] = f16bits(exp2f(sjl)) | (f16bits(exp2f(0.2f * sjl)) << 16);
    }
}

// ---------------------------------------------------------------------------
// K2: masked softmax + PV + residual + LayerNorm.  VERBATIM from R11:
// ef/mask LDS staging, exp-free pk-f16 score block (p = max(Ei*Ej, Fi*Fj)),
// 2-deep B prefetch, ones-B l-MFMA, parity combine, fused LN epilogue.
// ---------------------------------------------------------------------------
__global__ __launch_bounds__(1024, 4) void k2_attn(
        const float* __restrict__ x,
        const unsigned* __restrict__ adjbits,
        const unsigned* __restrict__ wxb16,
        const float* __restrict__ ai_s,
        const unsigned* __restrict__ ejfj,
        const float* __restrict__ gamma,
        const float* __restrict__ beta,
        float* __restrict__ out) {
    __shared__ unsigned efL[4][4096];    // 64 KB: (E|F<<16) per (h,j)
    __shared__ unsigned maskL[16][132];  // 8.4 KB (stride 132 -> 2-way, free)
    __shared__ float C_lds[4][16][32];   // 8 KB
    __shared__ float l_lds[4][16];

    const int t = threadIdx.x;
    const int i0 = blockIdx.x * 16;
    const int w = t >> 6, l = t & 63;
    const int h = w & 3, p = w >> 2;     // p in 0..3
    const int m = l & 15, q = l >> 4;

    {   // stage ejfj (all 4 heads), coalesced u32x4
        const u32x4* src = (const u32x4*)ejfj;
        u32x4* dst = (u32x4*)&efL[0][0];
        #pragma unroll
        for (int g = 0; g < 4; ++g) dst[t + 1024 * g] = src[t + 1024 * g];
    }
    {   // stage adjacency bitmask rows i0..i0+15
        #pragma unroll
        for (int g = 0; g < 2; ++g) {
            int idx = t + 1024 * g;
            int r = idx >> 7, c = idx & 127;
            maskL[r][c] = adjbits[(long)(i0 + r) * 128 + c];
        }
    }
    const float aif = ai_s[(i0 + m) * 4 + h];
    const _Float16 eiH = (_Float16)exp2f(aif);
    const _Float16 fiH = (_Float16)exp2f(0.2f * aif);
    const f16x2 Ei2 = {eiH, eiH};
    const f16x2 Fi2 = {fiH, fiH};
    __syncthreads();

    const unsigned* bp16 = wxb16 + ((2 * h) * 64 + l) * 4;  // + ks*2048 dwords
    const unsigned* efh = &efL[h][0] + q * 8;
    const s16x8 ONESH = {0x3C00, 0x3C00, 0x3C00, 0x3C00,
                         0x3C00, 0x3C00, 0x3C00, 0x3C00};

    f32x4 acc0 = {0.f, 0.f, 0.f, 0.f}, acc1 = {0.f, 0.f, 0.f, 0.f};
    f32x4 accl = {0.f, 0.f, 0.f, 0.f};

    // 2-deep B prefetch (both fblk halves)
    const int ks1 = (p + 4 < 128) ? p + 4 : p;
    u32x4 pa0 = *(const u32x4*)(bp16 + p * 2048);
    u32x4 pb0 = *(const u32x4*)(bp16 + p * 2048 + 256);
    u32x4 pa1 = *(const u32x4*)(bp16 + ks1 * 2048);
    u32x4 pb1 = *(const u32x4*)(bp16 + ks1 * 2048 + 256);

    for (int ks = p; ks < 128; ks += 4) {   // 32 j per step
        const int ksn2 = (ks + 8 < 128) ? (ks + 8) : ks;
        u32x4 pa2 = *(const u32x4*)(bp16 + ksn2 * 2048);
        u32x4 pb2 = *(const u32x4*)(bp16 + ksn2 * 2048 + 256);

        unsigned mq = (maskL[m][ks] >> (q * 8)) & 0xffu;
        u32x4 ef0 = *(const u32x4*)(efh + ks * 32);      // j0..j0+3
        u32x4 ef1 = *(const u32x4*)(efh + ks * 32 + 4);  // j0+4..j0+7
        unsigned efu[8] = {ef0.x, ef0.y, ef0.z, ef0.w, ef1.x, ef1.y, ef1.z, ef1.w};

        union { s16x8 v; unsigned u[4]; } af;
        #pragma unroll
        for (int pr = 0; pr < 4; ++pr) {
            unsigned d0 = efu[2 * pr], d1 = efu[2 * pr + 1];
            unsigned Ep = __builtin_amdgcn_perm(d1, d0, 0x05040100);  // (E_j0, E_j1)
            unsigned Fp = __builtin_amdgcn_perm(d1, d0, 0x07060302);  // (F_j0, F_j1)
            f16x2 mE = Ei2 * __builtin_bit_cast(f16x2, Ep);
            f16x2 mF = Fi2 * __builtin_bit_cast(f16x2, Fp);
            f16x2 mx = __builtin_elementwise_max(mE, mF);
            unsigned lo = (unsigned)(-(int)((mq >> (2 * pr)) & 1u));
            unsigned hi = (unsigned)(-(int)((mq >> (2 * pr + 1)) & 1u));
            unsigned msk = (lo & 0xFFFFu) | (hi & 0xFFFF0000u);
            af.u[pr] = __builtin_bit_cast(unsigned, mx) & msk;
        }
        union { u32x4 u; s16x8 s; } b0c, b1c;
        b0c.u = pa0; b1c.u = pb0;
        acc0 = __builtin_amdgcn_mfma_f32_16x16x32_f16(af.v, b0c.s, acc0, 0, 0, 0);
        acc1 = __builtin_amdgcn_mfma_f32_16x16x32_f16(af.v, b1c.s, acc1, 0, 0, 0);
        accl = __builtin_amdgcn_mfma_f32_16x16x32_f16(af.v, ONESH, accl, 0, 0, 0);
        pa0 = pa1; pb0 = pb1; pa1 = pa2; pb1 = pb2;
    }

    // combine the 4 parity partials
    if (p == 0) {
        #pragma unroll
        for (int reg = 0; reg < 4; ++reg) {
            C_lds[h][q * 4 + reg][m] = acc0[reg];
            C_lds[h][q * 4 + reg][16 + m] = acc1[reg];
            if (m == 0) l_lds[h][q * 4 + reg] = accl[reg];
        }
    }
    __syncthreads();
    if (p == 1) {
        #pragma unroll
        for (int reg = 0; reg < 4; ++reg) {
            C_lds[h][q * 4 + reg][m] += acc0[reg];
            C_lds[h][q * 4 + reg][16 + m] += acc1[reg];
            if (m == 0) l_lds[h][q * 4 + reg] += accl[reg];
        }
    }
    __syncthreads();
    if (p == 2) {
        #pragma unroll
        for (int reg = 0; reg < 4; ++reg) {
            C_lds[h][q * 4 + reg][m] += acc0[reg];
            C_lds[h][q * 4 + reg][16 + m] += acc1[reg];
            if (m == 0) l_lds[h][q * 4 + reg] += accl[reg];
        }
    }
    __syncthreads();
    if (p == 3) {
        #pragma unroll
        for (int reg = 0; reg < 4; ++reg) {
            C_lds[h][q * 4 + reg][m] += acc0[reg];
            C_lds[h][q * 4 + reg][16 + m] += acc1[reg];
            if (m == 0) l_lds[h][q * 4 + reg] += accl[reg];
        }
    }
    __syncthreads();

    // epilogue: normalize, residual, LayerNorm.
    if (t < 512) {
        const int r = t >> 5, c32 = t & 31;
        const int f0 = c32 * 4;
        const int hh = f0 >> 5, cl = f0 & 31;
        const float linv = 1.0f / l_lds[hh][r];
        f32x4 xv = *(const f32x4*)(x + (long)(i0 + r) * 128 + f0);
        float y[4], s1 = 0.f, s2 = 0.f;
        #pragma unroll
        for (int kk = 0; kk < 4; ++kk) {
            float yy = C_lds[hh][r][cl + kk] * linv + xv[kk];
            y[kk] = yy; s1 += yy; s2 += yy * yy;
        }
        #pragma unroll
        for (int s = 1; s <= 16; s <<= 1) {
            s1 += __shfl_xor(s1, s, 64);
            s2 += __shfl_xor(s2, s, 64);
        }
        const float mean = s1 * (1.0f / 128.0f);
        const float var = s2 * (1.0f / 128.0f) - mean * mean;
        const float rstd = rsqrtf(var + 1e-5f);
        f32x4 gv = *(const f32x4*)(gamma + f0);
        f32x4 bv = *(const f32x4*)(beta + f0);
        f32x4 ov;
        #pragma unroll
        for (int kk = 0; kk < 4; ++kk)
            ov[kk] = gv[kk] * ((y[kk] - mean) * rstd) + bv[kk];
        *(f32x4*)(out + (long)(i0 + r) * 128 + f0) = ov;
    }
}

extern "C" void kernel_launch(void* const* d_in, const int* in_sizes, int n_in,
                              void* d_out, int out_size, void* d_ws, size_t ws_size,
                              hipStream_t stream) {
    const float* x = (const float*)d_in[0];
    const unsigned* adj_raw = (const unsigned*)d_in[1];
    const float* W = (const float*)d_in[2];
    const float* a = (const float*)d_in[3];
    const float* gamma = (const float*)d_in[4];
    const float* beta = (const float*)d_in[5];

    unsigned* wxb16 = (unsigned*)d_ws;                                  // 1 MB
    float* ai_s = (float*)((char*)d_ws + (1 << 20));                    // 64 KB
    unsigned* ejfj = (unsigned*)((char*)d_ws + (1 << 20) + (64 << 10)); // 64 KB
    unsigned* adjbits = (unsigned*)((char*)d_ws + (2 << 20));           // 2 MB

    k01<<<2304, 256, 0, stream>>>(adj_raw, x, W, a, adjbits, wxb16, ai_s, ejfj);
    k2_attn<<<256, 1024, 0, stream>>>(x, adjbits, wxb16, ai_s, ejfj, gamma, beta,
                                      (float*)d_out);
}